// Round 1
// baseline (3833.282 us; speedup 1.0000x reference)
//
#include <hip/hip_runtime.h>
#include <cstddef>
#include <cstdint>
#include <math.h>

#define Bsz   2
#define Sdim  2048
#define Hn    16
#define Ddim  1024
#define DEPTH 64
#define Mrows (Bsz * Sdim)
#define QTILES (Sdim / 64)

typedef __attribute__((ext_vector_type(8))) short short8v;
typedef __attribute__((ext_vector_type(4))) float f32x4;

// ---------------------------------------------------------------------------
// fp32 -> packed (bf16 hi | bf16 lo) in one u32.
// hi = truncated top 16 bits (exact); lo = RNE-bf16 of the residual.
// hi+lo carries ~17 mantissa bits -> split-bf16 GEMM error ~1e-4 relative.
// ---------------------------------------------------------------------------
__device__ __forceinline__ uint32_t pack_hl(float x) {
    const uint32_t u  = __float_as_uint(x);
    const uint32_t hi = u & 0xFFFF0000u;
    const float    r  = x - __uint_as_float(hi);
    const uint32_t v  = __float_as_uint(r);
    const uint32_t lo = (v + 0x7FFFu + ((v >> 16) & 1u)) >> 16;
    return hi | lo;
}

// unpack 8 packed elems (2x uint4) into hi / lo bf16 fragments (short8).
// unit q of the fragment holds elems (2q, 2q+1): elem 2q in bits[15:0].
__device__ __forceinline__ void unpack_frag(const uint4& r0, const uint4& r1,
                                            short8v& hi, short8v& lo)
{
    union { uint32_t u[4]; short8v v; } H, L;
    const uint32_t p[8] = {r0.x, r0.y, r0.z, r0.w, r1.x, r1.y, r1.z, r1.w};
#pragma unroll
    for (int q = 0; q < 4; ++q) {
        const uint32_t p0 = p[2 * q], p1 = p[2 * q + 1];
        H.u[q] = (p0 >> 16) | (p1 & 0xFFFF0000u);
        L.u[q] = (p0 & 0xFFFFu) | (p1 << 16);
    }
    hi = H.v; lo = L.v;
}

// ---------------------------------------------------------------------------
// Pack + transpose a 1024x1024 weight: Wt[n][k] = pack_hl(W[k][n]).
// 64x64 tiles through LDS so both global read and write are coalesced.
// ---------------------------------------------------------------------------
__global__ __launch_bounds__(256) void pack_w_kernel(const float* __restrict__ W,
                                                     uint32_t* __restrict__ Wt)
{
    __shared__ uint32_t T[64][65];
    const int n0  = blockIdx.x * 64;
    const int k0  = blockIdx.y * 64;
    const int tid = threadIdx.x;
    const int c   = tid & 63;
    const int r0  = tid >> 6;
#pragma unroll
    for (int i = 0; i < 16; ++i) {
        const int kk = r0 * 16 + i;
        T[c][kk] = pack_hl(W[(size_t)(k0 + kk) * 1024 + n0 + c]);
    }
    __syncthreads();
#pragma unroll
    for (int i = 0; i < 16; ++i) {
        const int nn = r0 * 16 + i;
        Wt[(size_t)(n0 + nn) * 1024 + k0 + c] = T[nn][c];
    }
}

// ---------------------------------------------------------------------------
// Split-bf16 MFMA GEMM: Y = X(4096,1024) @ W(1024,1024) + bias.
// 128x128 tile, 256 threads = 4 waves (2x2), BK=32.
// A: fp32 global -> pack on the fly -> LDS [128][36] u32 (padded, bank-clean).
// B: pre-packed+transposed Wt[n][k] -> direct dwordx4 fragment loads (L2-hot).
// 3 MFMAs per fragment pair: hi*hi + hi*lo + lo*hi (lo*lo ~2^-34, dropped).
// C/D layout (HW-verified): col = lane&15, row = (lane>>4)*4 + reg.
// A/B fragment k-order: any consistent bijection cancels between A and B.
// ---------------------------------------------------------------------------
template <bool SPLIT>
__device__ __forceinline__ void mfma_gemm(const float* __restrict__ X,
                                          const uint32_t* __restrict__ Wt,
                                          const float* __restrict__ bias,
                                          float* __restrict__ Y)
{
    constexpr int K = 1024;
    __shared__ __align__(16) uint32_t Apk[128][36];

    const int tid  = threadIdx.x;
    const int lane = tid & 63;
    const int wid  = tid >> 6;
    const int wr   = wid >> 1;     // wave row (0..1) -> 64 rows
    const int wc   = wid & 1;      // wave col (0..1) -> 64 cols
    const int l15  = lane & 15;
    const int lg   = lane >> 4;    // k-group 0..3

    const int m0 = blockIdx.y * 128;
    const int n0 = blockIdx.x * 128;

    const int sr = tid >> 3;         // staging row base 0..31
    const int sk = (tid & 7) * 4;    // staging k elem 0..28

    const uint32_t* wp[4];
#pragma unroll
    for (int fj = 0; fj < 4; ++fj)
        wp[fj] = Wt + (size_t)(n0 + wc * 64 + fj * 16 + l15) * K + lg * 8;

    f32x4 acc[4][4] = {};

    for (int k0 = 0; k0 < K; k0 += 32) {
        // B fragment loads (global, packed, no LDS dependency -> issue early)
        uint4 braw[4][2];
#pragma unroll
        for (int fj = 0; fj < 4; ++fj) {
            braw[fj][0] = *reinterpret_cast<const uint4*>(wp[fj] + k0);
            braw[fj][1] = *reinterpret_cast<const uint4*>(wp[fj] + k0 + 4);
        }

        // A tile: fp32 load (8x128B segments/instr) + convert
        uint4 apk[4];
#pragma unroll
        for (int i = 0; i < 4; ++i) {
            const float4 xv = *reinterpret_cast<const float4*>(
                &X[(size_t)(m0 + sr + i * 32) * K + k0 + sk]);
            apk[i].x = pack_hl(xv.x);
            apk[i].y = pack_hl(xv.y);
            apk[i].z = pack_hl(xv.z);
            apk[i].w = pack_hl(xv.w);
        }

        __syncthreads();   // previous iteration's fragment reads done
#pragma unroll
        for (int i = 0; i < 4; ++i)
            *reinterpret_cast<uint4*>(&Apk[sr + i * 32][sk]) = apk[i];
        __syncthreads();

        short8v bhi[4], blo[4];
#pragma unroll
        for (int fj = 0; fj < 4; ++fj)
            unpack_frag(braw[fj][0], braw[fj][1], bhi[fj], blo[fj]);

#pragma unroll
        for (int fi = 0; fi < 4; ++fi) {
            const uint32_t* ap = &Apk[wr * 64 + fi * 16 + l15][lg * 8];
            const uint4 a0 = *reinterpret_cast<const uint4*>(ap);
            const uint4 a1 = *reinterpret_cast<const uint4*>(ap + 4);
            short8v ahi, alo;
            unpack_frag(a0, a1, ahi, alo);
#pragma unroll
            for (int fj = 0; fj < 4; ++fj) {
                acc[fi][fj] = __builtin_amdgcn_mfma_f32_16x16x32_bf16(
                    ahi, bhi[fj], acc[fi][fj], 0, 0, 0);
                acc[fi][fj] = __builtin_amdgcn_mfma_f32_16x16x32_bf16(
                    ahi, blo[fj], acc[fi][fj], 0, 0, 0);
                acc[fi][fj] = __builtin_amdgcn_mfma_f32_16x16x32_bf16(
                    alo, bhi[fj], acc[fi][fj], 0, 0, 0);
            }
        }
    }

    // epilogue: bias + store (16 consecutive cols per lane-group -> coalesced)
#pragma unroll
    for (int fj = 0; fj < 4; ++fj) {
        const int col = n0 + wc * 64 + fj * 16 + l15;
        const float bv = bias[col];
#pragma unroll
        for (int fi = 0; fi < 4; ++fi) {
#pragma unroll
            for (int j = 0; j < 4; ++j) {
                const int row = m0 + wr * 64 + fi * 16 + lg * 4 + j;
                const float val = acc[fi][fj][j] + bv;
                if (SPLIT) {
                    const int bb = row >> 11;     // / Sdim
                    const int ss = row & 2047;
                    const int hh = col >> 6;      // / DEPTH
                    const int dd = col & 63;
                    Y[(((size_t)bb * Hn + hh) * Sdim + ss) * DEPTH + dd] = val;
                } else {
                    Y[(size_t)row * Ddim + col] = val;
                }
            }
        }
    }
}

__global__ __launch_bounds__(256) void proj_kernel(
    const float* __restrict__ q, const float* __restrict__ k,
    const float* __restrict__ v,
    const uint32_t* __restrict__ WtQ, const uint32_t* __restrict__ WtK,
    const uint32_t* __restrict__ WtV,
    const float* __restrict__ bq, const float* __restrict__ bk,
    const float* __restrict__ bv,
    float* __restrict__ qh, float* __restrict__ kh, float* __restrict__ vh)
{
    const float* X; const uint32_t* W; const float* bias; float* Y;
    switch (blockIdx.z) {
        case 0:  X = q; W = WtQ; bias = bq; Y = qh; break;
        case 1:  X = k; W = WtK; bias = bk; Y = kh; break;
        default: X = v; W = WtV; bias = bv; Y = vh; break;
    }
    mfma_gemm<true>(X, W, bias, Y);
}

__global__ __launch_bounds__(256) void oproj_kernel(
    const float* __restrict__ ctx, const uint32_t* __restrict__ WtO,
    const float* __restrict__ bo, float* __restrict__ out)
{
    mfma_gemm<false>(ctx, WtO, bo, out);
}

// ---------------------------------------------------------------------------
// Tiled attention: UNCHANGED from the verified 4066 µs kernel.
// One block per 64-row Q-tile per (b,h); pass 1 stats, pass 2 attn write + PV.
// ---------------------------------------------------------------------------
__global__ __launch_bounds__(256) void attn_tile_kernel(
    const float* __restrict__ qh, const float* __restrict__ kh,
    const float* __restrict__ vh,
    float* __restrict__ attn, float* __restrict__ ctx)
{
    __shared__ float Qs[64][65];
    __shared__ float Ks[64][65];   // aliased as Ps in pass 2
    __shared__ float Vs[64][65];

    const int qt  = (QTILES - 1) - blockIdx.x;   // heavy tiles dispatch first
    const int h   = blockIdx.y;
    const int b   = blockIdx.z;
    const int tid = threadIdx.x;
    const int tx  = tid & 15;     // 4 cols: tx*4..+3
    const int ty  = tid >> 4;     // 4 rows: ty*4..+3

    const size_t head_base = ((size_t)(b * Hn + h)) * Sdim * DEPTH;
    const int q0 = qt * 64;
    const float scale = 0.125f;   // 1/sqrt(64)

    // load Q tile
    for (int i = tid; i < 64 * 16; i += 256) {
        const int r = i >> 4, c4 = (i & 15) << 2;
        *reinterpret_cast<float4*>(&Qs[r][c4]) =
            *reinterpret_cast<const float4*>(
                &qh[head_base + (size_t)(q0 + r) * DEPTH + c4]);
    }

    float m_r[4], s_r[4];
#pragma unroll
    for (int i = 0; i < 4; ++i) { m_r[i] = -INFINITY; s_r[i] = 0.f; }

    // ---------------- pass 1: stats ----------------
    for (int kt = 0; kt <= qt; ++kt) {
        __syncthreads();
        const int k0 = kt * 64;
        for (int i = tid; i < 64 * 16; i += 256) {
            const int r = i >> 4, c4 = (i & 15) << 2;
            *reinterpret_cast<float4*>(&Ks[r][c4]) =
                *reinterpret_cast<const float4*>(
                    &kh[head_base + (size_t)(k0 + r) * DEPTH + c4]);
        }
        __syncthreads();

        float acc[4][4] = {};
#pragma unroll
        for (int kk4 = 0; kk4 < 64; kk4 += 4) {
            float4 a4[4], b4[4];
#pragma unroll
            for (int i = 0; i < 4; ++i)
                a4[i] = *reinterpret_cast<const float4*>(&Qs[ty * 4 + i][kk4]);
#pragma unroll
            for (int j = 0; j < 4; ++j)
                b4[j] = *reinterpret_cast<const float4*>(&Ks[tx * 4 + j][kk4]);
#pragma unroll
            for (int i = 0; i < 4; ++i)
#pragma unroll
                for (int j = 0; j < 4; ++j)
                    acc[i][j] += a4[i].x * b4[j].x + a4[i].y * b4[j].y +
                                 a4[i].z * b4[j].z + a4[i].w * b4[j].w;
        }

        const bool diag = (kt == qt);
#pragma unroll
        for (int i = 0; i < 4; ++i) {
            const int qg = q0 + ty * 4 + i;
            float tmax = -INFINITY;
#pragma unroll
            for (int j = 0; j < 4; ++j) {
                float l = acc[i][j] * scale;
                if (diag && (kt * 64 + tx * 4 + j > qg)) l = -INFINITY;
                acc[i][j] = l;
                tmax = fmaxf(tmax, l);
            }
            tmax = fmaxf(tmax, __shfl_xor(tmax, 1, 64));
            tmax = fmaxf(tmax, __shfl_xor(tmax, 2, 64));
            tmax = fmaxf(tmax, __shfl_xor(tmax, 4, 64));
            tmax = fmaxf(tmax, __shfl_xor(tmax, 8, 64));

            const float mnew = fmaxf(m_r[i], tmax);
            float psum = 0.f;
#pragma unroll
            for (int j = 0; j < 4; ++j)
                psum += (acc[i][j] <= -1e37f) ? 0.f : expf(acc[i][j] - mnew);
            psum += __shfl_xor(psum, 1, 64);
            psum += __shfl_xor(psum, 2, 64);
            psum += __shfl_xor(psum, 4, 64);
            psum += __shfl_xor(psum, 8, 64);

            const float corr = (m_r[i] <= -1e37f) ? 0.f : expf(m_r[i] - mnew);
            s_r[i] = s_r[i] * corr + psum;
            m_r[i] = mnew;
        }
    }

    float inv_s[4];
#pragma unroll
    for (int i = 0; i < 4; ++i) inv_s[i] = 1.f / s_r[i];

    float accv[4][4] = {};  // ctx accumulator: rows ty*4+i, d-cols tx*4+j

    // ---------------- pass 2: attn write + PV ----------------
    for (int kt = 0; kt <= qt; ++kt) {
        __syncthreads();   // prior iteration done reading Ps/Vs
        const int k0 = kt * 64;
        for (int i = tid; i < 64 * 16; i += 256) {
            const int r = i >> 4, c4 = (i & 15) << 2;
            const size_t src = head_base + (size_t)(k0 + r) * DEPTH + c4;
            *reinterpret_cast<float4*>(&Ks[r][c4]) =
                *reinterpret_cast<const float4*>(&kh[src]);
            *reinterpret_cast<float4*>(&Vs[r][c4]) =
                *reinterpret_cast<const float4*>(&vh[src]);
        }
        __syncthreads();

        float acc[4][4] = {};
#pragma unroll
        for (int kk4 = 0; kk4 < 64; kk4 += 4) {
            float4 a4[4], b4[4];
#pragma unroll
            for (int i = 0; i < 4; ++i)
                a4[i] = *reinterpret_cast<const float4*>(&Qs[ty * 4 + i][kk4]);
#pragma unroll
            for (int j = 0; j < 4; ++j)
                b4[j] = *reinterpret_cast<const float4*>(&Ks[tx * 4 + j][kk4]);
#pragma unroll
            for (int i = 0; i < 4; ++i)
#pragma unroll
                for (int j = 0; j < 4; ++j)
                    acc[i][j] += a4[i].x * b4[j].x + a4[i].y * b4[j].y +
                                 a4[i].z * b4[j].z + a4[i].w * b4[j].w;
        }

        const bool diag = (kt == qt);
#pragma unroll
        for (int i = 0; i < 4; ++i) {
            const int qg = q0 + ty * 4 + i;
#pragma unroll
            for (int j = 0; j < 4; ++j) {
                float p;
                if (diag && (k0 + tx * 4 + j > qg)) p = 0.f;
                else p = expf(acc[i][j] * scale - m_r[i]) * inv_s[i];
                acc[i][j] = p;
            }
            // write attn row segment (float4, coalesced across tx)
            const size_t arow =
                ((size_t)(b * Hn + h) * Sdim + qg) * Sdim + k0 + tx * 4;
            float4 pv = make_float4(acc[i][0], acc[i][1], acc[i][2], acc[i][3]);
            *reinterpret_cast<float4*>(&attn[arow]) = pv;
        }

        __syncthreads();   // all threads done reading Ks
        float (*Ps)[65] = Ks;  // alias
#pragma unroll
        for (int i = 0; i < 4; ++i)
            *reinterpret_cast<float4*>(&Ps[ty * 4 + i][tx * 4]) =
                make_float4(acc[i][0], acc[i][1], acc[i][2], acc[i][3]);
        __syncthreads();

#pragma unroll
        for (int kk4 = 0; kk4 < 64; kk4 += 4) {
            float4 a4[4];
#pragma unroll
            for (int i = 0; i < 4; ++i)
                a4[i] = *reinterpret_cast<const float4*>(&Ps[ty * 4 + i][kk4]);
#pragma unroll
            for (int kk = 0; kk < 4; ++kk) {
                float4 b4 = *reinterpret_cast<const float4*>(&Vs[kk4 + kk][tx * 4]);
                const float av0 = (kk == 0) ? a4[0].x : (kk == 1) ? a4[0].y : (kk == 2) ? a4[0].z : a4[0].w;
                const float av1 = (kk == 0) ? a4[1].x : (kk == 1) ? a4[1].y : (kk == 2) ? a4[1].z : a4[1].w;
                const float av2 = (kk == 0) ? a4[2].x : (kk == 1) ? a4[2].y : (kk == 2) ? a4[2].z : a4[2].w;
                const float av3 = (kk == 0) ? a4[3].x : (kk == 1) ? a4[3].y : (kk == 2) ? a4[3].z : a4[3].w;
                accv[0][0] += av0 * b4.x; accv[0][1] += av0 * b4.y; accv[0][2] += av0 * b4.z; accv[0][3] += av0 * b4.w;
                accv[1][0] += av1 * b4.x; accv[1][1] += av1 * b4.y; accv[1][2] += av1 * b4.z; accv[1][3] += av1 * b4.w;
                accv[2][0] += av2 * b4.x; accv[2][1] += av2 * b4.y; accv[2][2] += av2 * b4.z; accv[2][3] += av2 * b4.w;
                accv[3][0] += av3 * b4.x; accv[3][1] += av3 * b4.y; accv[3][2] += av3 * b4.z; accv[3][3] += av3 * b4.w;
            }
        }
    }

    // write ctx in concat layout (B, S, D)
#pragma unroll
    for (int i = 0; i < 4; ++i) {
        const int qg = q0 + ty * 4 + i;
        float4 cv = make_float4(accv[i][0], accv[i][1], accv[i][2], accv[i][3]);
        *reinterpret_cast<float4*>(
            &ctx[((size_t)b * Sdim + qg) * Ddim + h * DEPTH + tx * 4]) = cv;
    }
}

// ---------------------------------------------------------------------------
extern "C" void kernel_launch(void* const* d_in, const int* in_sizes, int n_in,
                              void* d_out, int out_size, void* d_ws, size_t ws_size,
                              hipStream_t stream)
{
    (void)in_sizes; (void)n_in; (void)out_size; (void)ws_size;

    const float* v  = (const float*)d_in[0];
    const float* k  = (const float*)d_in[1];
    const float* q  = (const float*)d_in[2];
    const float* Wq = (const float*)d_in[4];
    const float* bq = (const float*)d_in[5];
    const float* Wk = (const float*)d_in[6];
    const float* bk = (const float*)d_in[7];
    const float* Wv = (const float*)d_in[8];
    const float* bv = (const float*)d_in[9];
    const float* Wo = (const float*)d_in[10];
    const float* bo = (const float*)d_in[11];

    float* out  = (float*)d_out;
    float* attn = out + (size_t)Bsz * Sdim * Ddim;

    const size_t sz = (size_t)Bsz * Sdim * Ddim;
    float* ws  = (float*)d_ws;
    float* qh  = ws;
    float* kh  = qh + sz;
    float* vh  = kh + sz;
    float* ctx = vh + sz;

    // Workspace aliasing (stream-ordered, no extra footprint vs prior kernel):
    //   WtQ/WtK/WtV live in the ctx region (12 MB < 16.8 MB); consumed by proj
    //   before attn overwrites ctx.  WtO lives in the qh region, written only
    //   AFTER attn has consumed qh.
    uint32_t* WtQ = (uint32_t*)ctx;
    uint32_t* WtK = WtQ + 1024 * 1024;
    uint32_t* WtV = WtK + 1024 * 1024;
    uint32_t* WtO = (uint32_t*)qh;

    dim3 gpk(16, 16);
    pack_w_kernel<<<gpk, 256, 0, stream>>>(Wq, WtQ);
    pack_w_kernel<<<gpk, 256, 0, stream>>>(Wk, WtK);
    pack_w_kernel<<<gpk, 256, 0, stream>>>(Wv, WtV);

    dim3 gproj(Ddim / 128, Mrows / 128, 3);
    proj_kernel<<<gproj, 256, 0, stream>>>(q, k, v, WtQ, WtK, WtV,
                                           bq, bk, bv, qh, kh, vh);

    dim3 gattn(QTILES, Hn, Bsz);
    attn_tile_kernel<<<gattn, 256, 0, stream>>>(qh, kh, vh, attn, ctx);

    pack_w_kernel<<<gpk, 256, 0, stream>>>(Wo, WtO);

    dim3 gout(Ddim / 128, Mrows / 128);
    oproj_kernel<<<gout, 256, 0, stream>>>(ctx, WtO, bo, out);
}

// Round 3
// 1118.191 us; speedup vs baseline: 3.4281x; 3.4281x over previous
//
#include <hip/hip_runtime.h>
#include <cstddef>
#include <cstdint>
#include <math.h>

#define Bsz   2
#define Sdim  2048
#define Hn    16
#define Ddim  1024
#define DEPTH 64
#define Mrows (Bsz * Sdim)
#define QTILES (Sdim / 64)

typedef __attribute__((ext_vector_type(8))) short short8v;
typedef __attribute__((ext_vector_type(4))) float f32x4;

// ---------------------------------------------------------------------------
// fp32 -> packed (bf16 hi | bf16 lo) in one u32.
// hi = truncated top 16 bits (exact); lo = RNE-bf16 of the residual.
// hi+lo carries ~17 mantissa bits -> split-bf16 GEMM error ~1e-4 relative.
// ---------------------------------------------------------------------------
__device__ __forceinline__ uint32_t pack_hl(float x) {
    const uint32_t u  = __float_as_uint(x);
    const uint32_t hi = u & 0xFFFF0000u;
    const float    r  = x - __uint_as_float(hi);
    const uint32_t v  = __float_as_uint(r);
    const uint32_t lo = (v + 0x7FFFu + ((v >> 16) & 1u)) >> 16;
    return hi | lo;
}

// unpack 8 packed elems (2x uint4) into hi / lo bf16 fragments (short8).
// unit q of the fragment holds elems (2q, 2q+1): elem 2q in bits[15:0].
// Same slot->k bijection used for ALL A and B fragments -> cancels in MFMA.
__device__ __forceinline__ void unpack_frag(const uint4& r0, const uint4& r1,
                                            short8v& hi, short8v& lo)
{
    union { uint32_t u[4]; short8v v; } H, L;
    const uint32_t p[8] = {r0.x, r0.y, r0.z, r0.w, r1.x, r1.y, r1.z, r1.w};
#pragma unroll
    for (int q = 0; q < 4; ++q) {
        const uint32_t p0 = p[2 * q], p1 = p[2 * q + 1];
        H.u[q] = (p0 >> 16) | (p1 & 0xFFFF0000u);
        L.u[q] = (p0 & 0xFFFFu) | (p1 << 16);
    }
    hi = H.v; lo = L.v;
}

// ---------------------------------------------------------------------------
// Pack + transpose a 1024x1024 weight: Wt[n][k] = pack_hl(W[k][n]).
// ---------------------------------------------------------------------------
__global__ __launch_bounds__(256) void pack_w_kernel(const float* __restrict__ W,
                                                     uint32_t* __restrict__ Wt)
{
    __shared__ uint32_t T[64][65];
    const int n0  = blockIdx.x * 64;
    const int k0  = blockIdx.y * 64;
    const int tid = threadIdx.x;
    const int c   = tid & 63;
    const int r0  = tid >> 6;
#pragma unroll
    for (int i = 0; i < 16; ++i) {
        const int kk = r0 * 16 + i;
        T[c][kk] = pack_hl(W[(size_t)(k0 + kk) * 1024 + n0 + c]);
    }
    __syncthreads();
#pragma unroll
    for (int i = 0; i < 16; ++i) {
        const int nn = r0 * 16 + i;
        Wt[(size_t)(n0 + nn) * 1024 + k0 + c] = T[nn][c];
    }
}

// ---------------------------------------------------------------------------
// Split-bf16 MFMA GEMM: Y = X(4096,1024) @ W(1024,1024) + bias, 128x128 tile.
// PACK: store packed u32 (hi|lo) output (for attention inputs), else fp32.
// oscale: multiplied into the output (0.125 for Q pre-scaling, exact pow2).
// ---------------------------------------------------------------------------
template <bool SPLIT, bool PACK>
__device__ __forceinline__ void mfma_gemm(const float* __restrict__ X,
                                          const uint32_t* __restrict__ Wt,
                                          const float* __restrict__ bias,
                                          void* __restrict__ Yv,
                                          float oscale)
{
    constexpr int K = 1024;
    __shared__ __align__(16) uint32_t Apk[128][36];

    const int tid  = threadIdx.x;
    const int lane = tid & 63;
    const int wid  = tid >> 6;
    const int wr   = wid >> 1;
    const int wc   = wid & 1;
    const int l15  = lane & 15;
    const int lg   = lane >> 4;

    const int m0 = blockIdx.y * 128;
    const int n0 = blockIdx.x * 128;

    const int sr = tid >> 3;
    const int sk = (tid & 7) * 4;

    const uint32_t* wp[4];
#pragma unroll
    for (int fj = 0; fj < 4; ++fj)
        wp[fj] = Wt + (size_t)(n0 + wc * 64 + fj * 16 + l15) * K + lg * 8;

    f32x4 acc[4][4] = {};

    for (int k0 = 0; k0 < K; k0 += 32) {
        uint4 braw[4][2];
#pragma unroll
        for (int fj = 0; fj < 4; ++fj) {
            braw[fj][0] = *reinterpret_cast<const uint4*>(wp[fj] + k0);
            braw[fj][1] = *reinterpret_cast<const uint4*>(wp[fj] + k0 + 4);
        }

        uint4 apk[4];
#pragma unroll
        for (int i = 0; i < 4; ++i) {
            const float4 xv = *reinterpret_cast<const float4*>(
                &X[(size_t)(m0 + sr + i * 32) * K + k0 + sk]);
            apk[i].x = pack_hl(xv.x);
            apk[i].y = pack_hl(xv.y);
            apk[i].z = pack_hl(xv.z);
            apk[i].w = pack_hl(xv.w);
        }

        __syncthreads();
#pragma unroll
        for (int i = 0; i < 4; ++i)
            *reinterpret_cast<uint4*>(&Apk[sr + i * 32][sk]) = apk[i];
        __syncthreads();

        short8v bhi[4], blo[4];
#pragma unroll
        for (int fj = 0; fj < 4; ++fj)
            unpack_frag(braw[fj][0], braw[fj][1], bhi[fj], blo[fj]);

#pragma unroll
        for (int fi = 0; fi < 4; ++fi) {
            const uint32_t* ap = &Apk[wr * 64 + fi * 16 + l15][lg * 8];
            const uint4 a0 = *reinterpret_cast<const uint4*>(ap);
            const uint4 a1 = *reinterpret_cast<const uint4*>(ap + 4);
            short8v ahi, alo;
            unpack_frag(a0, a1, ahi, alo);
#pragma unroll
            for (int fj = 0; fj < 4; ++fj) {
                acc[fi][fj] = __builtin_amdgcn_mfma_f32_16x16x32_bf16(
                    ahi, bhi[fj], acc[fi][fj], 0, 0, 0);
                acc[fi][fj] = __builtin_amdgcn_mfma_f32_16x16x32_bf16(
                    ahi, blo[fj], acc[fi][fj], 0, 0, 0);
                acc[fi][fj] = __builtin_amdgcn_mfma_f32_16x16x32_bf16(
                    alo, bhi[fj], acc[fi][fj], 0, 0, 0);
            }
        }
    }

#pragma unroll
    for (int fj = 0; fj < 4; ++fj) {
        const int col = n0 + wc * 64 + fj * 16 + l15;
        const float bv = bias[col];
#pragma unroll
        for (int fi = 0; fi < 4; ++fi) {
#pragma unroll
            for (int j = 0; j < 4; ++j) {
                const int row = m0 + wr * 64 + fi * 16 + lg * 4 + j;
                const float val = (acc[fi][fj][j] + bv) * oscale;
                size_t idx;
                if (SPLIT) {
                    const int bb = row >> 11;
                    const int ss = row & 2047;
                    const int hh = col >> 6;
                    const int dd = col & 63;
                    idx = (((size_t)bb * Hn + hh) * Sdim + ss) * DEPTH + dd;
                } else {
                    idx = (size_t)row * Ddim + col;
                }
                if (PACK) ((uint32_t*)Yv)[idx] = pack_hl(val);
                else      ((float*)Yv)[idx]    = val;
            }
        }
    }
}

__global__ __launch_bounds__(256) void proj_kernel(
    const float* __restrict__ q, const float* __restrict__ k,
    const float* __restrict__ v,
    const uint32_t* __restrict__ WtQ, const uint32_t* __restrict__ WtK,
    const uint32_t* __restrict__ WtV,
    const float* __restrict__ bq, const float* __restrict__ bk,
    const float* __restrict__ bv,
    uint32_t* __restrict__ qh, uint32_t* __restrict__ kh,
    uint32_t* __restrict__ vh)
{
    const float* X; const uint32_t* W; const float* bias; uint32_t* Y;
    float sc = 1.0f;
    switch (blockIdx.z) {
        case 0:  X = q; W = WtQ; bias = bq; Y = qh; sc = 0.125f; break;
        case 1:  X = k; W = WtK; bias = bk; Y = kh; break;
        default: X = v; W = WtV; bias = bv; Y = vh; break;
    }
    mfma_gemm<true, true>(X, W, bias, Y, sc);
}

__global__ __launch_bounds__(256) void oproj_kernel(
    const float* __restrict__ ctx, const uint32_t* __restrict__ WtO,
    const float* __restrict__ bo, float* __restrict__ out)
{
    mfma_gemm<false, false>(ctx, WtO, bo, out, 1.0f);
}

// ---------------------------------------------------------------------------
// MFMA attention. One block (4 waves) per 64-row Q-tile per (b,h).
// Wave w owns q-rows w*16..+15. Q fragments hoisted to registers (packed in,
// pre-scaled by 0.125). K fragments read straight from global (L2-hot, no
// LDS). Pass 1: QK^T MFMA + online max/sum (no barriers). Pass 2: QK^T,
// p = exp(l-m)/s, direct attn stores, P packed->LDS + V transposed->LDS
// (stride-68 pad), PV MFMA accumulate.  XCD-chunked block mapping: the 32
// q-tiles of one (b,h) share an XCD (K/V ~1MB L2-resident); heavy first.
// ---------------------------------------------------------------------------
__device__ __forceinline__ void qk_tile(const uint32_t* __restrict__ kh_head,
                                        int k0, int l15, int lg,
                                        const short8v* qhi, const short8v* qlo,
                                        f32x4* sacc)
{
#pragma unroll
    for (int fc = 0; fc < 4; ++fc) {
        const uint32_t* p = kh_head + (size_t)(k0 + fc * 16 + l15) * DEPTH + lg * 8;
        const uint4 r00 = *reinterpret_cast<const uint4*>(p);
        const uint4 r01 = *reinterpret_cast<const uint4*>(p + 4);
        const uint4 r10 = *reinterpret_cast<const uint4*>(p + 32);
        const uint4 r11 = *reinterpret_cast<const uint4*>(p + 36);
        short8v khi, klo;
        unpack_frag(r00, r01, khi, klo);
        sacc[fc] = __builtin_amdgcn_mfma_f32_16x16x32_bf16(qhi[0], khi, sacc[fc], 0, 0, 0);
        sacc[fc] = __builtin_amdgcn_mfma_f32_16x16x32_bf16(qhi[0], klo, sacc[fc], 0, 0, 0);
        sacc[fc] = __builtin_amdgcn_mfma_f32_16x16x32_bf16(qlo[0], khi, sacc[fc], 0, 0, 0);
        unpack_frag(r10, r11, khi, klo);
        sacc[fc] = __builtin_amdgcn_mfma_f32_16x16x32_bf16(qhi[1], khi, sacc[fc], 0, 0, 0);
        sacc[fc] = __builtin_amdgcn_mfma_f32_16x16x32_bf16(qhi[1], klo, sacc[fc], 0, 0, 0);
        sacc[fc] = __builtin_amdgcn_mfma_f32_16x16x32_bf16(qlo[1], khi, sacc[fc], 0, 0, 0);
    }
}

__global__ __launch_bounds__(256) void attn_mfma_kernel(
    const uint32_t* __restrict__ qpk, const uint32_t* __restrict__ kpk,
    const uint32_t* __restrict__ vpk,
    float* __restrict__ attn, float* __restrict__ ctx)
{
    __shared__ __align__(16) uint32_t Vt[64][68];  // V^T tile: [d][key]
    __shared__ __align__(16) uint32_t Ps[64][68];  // P packed: [qrow][key]

    // block mapping: xcd = n&7 keeps all q-tiles of a (b,h) on one XCD
    const int n   = blockIdx.x;
    const int xcd = n & 7;
    const int s   = n >> 3;
    const int c   = ((s >> 5) << 3) | xcd;    // (b,h) combo 0..31
    const int qt  = 31 - (s & 31);            // heavy tiles first
    const int b   = c >> 4;
    const int h   = c & 15;

    const int tid  = threadIdx.x;
    const int lane = tid & 63;
    const int wid  = tid >> 6;
    const int l15  = lane & 15;
    const int lg   = lane >> 4;

    const size_t head = ((size_t)(b * Hn + h)) * Sdim * DEPTH;
    const int q0 = qt * 64;

    const uint32_t* kh_head = kpk + head;
    const uint32_t* vh_head = vpk + head;

    // ---- Q fragments (already scaled by 1/8) hoisted into registers ----
    short8v qhi[2], qlo[2];
    {
        const uint32_t* qp = qpk + head +
            (size_t)(q0 + wid * 16 + l15) * DEPTH + lg * 8;
#pragma unroll
        for (int kk = 0; kk < 2; ++kk) {
            const uint4 r0 = *reinterpret_cast<const uint4*>(qp + kk * 32);
            const uint4 r1 = *reinterpret_cast<const uint4*>(qp + kk * 32 + 4);
            unpack_frag(r0, r1, qhi[kk], qlo[kk]);
        }
    }

    float m_r[4], s_r[4];
#pragma unroll
    for (int j = 0; j < 4; ++j) { m_r[j] = -INFINITY; s_r[j] = 0.f; }

    // ---------------- pass 1: stats (no LDS, no barriers) ----------------
    for (int kt = 0; kt <= qt; ++kt) {
        const int k0 = kt * 64;
        f32x4 sacc[4] = {};
        qk_tile(kh_head, k0, l15, lg, qhi, qlo, sacc);

        const bool diag = (kt == qt);
#pragma unroll
        for (int j = 0; j < 4; ++j) {
            const int qg = q0 + wid * 16 + lg * 4 + j;
            float v0 = sacc[0][j], v1 = sacc[1][j], v2 = sacc[2][j], v3 = sacc[3][j];
            if (diag) {
                if (k0 +  0 + l15 > qg) v0 = -INFINITY;
                if (k0 + 16 + l15 > qg) v1 = -INFINITY;
                if (k0 + 32 + l15 > qg) v2 = -INFINITY;
                if (k0 + 48 + l15 > qg) v3 = -INFINITY;
            }
            float tmax = fmaxf(fmaxf(v0, v1), fmaxf(v2, v3));
            tmax = fmaxf(tmax, __shfl_xor(tmax, 1, 64));
            tmax = fmaxf(tmax, __shfl_xor(tmax, 2, 64));
            tmax = fmaxf(tmax, __shfl_xor(tmax, 4, 64));
            tmax = fmaxf(tmax, __shfl_xor(tmax, 8, 64));

            const float mnew = fmaxf(m_r[j], tmax);
            float ps = __expf(v0 - mnew) + __expf(v1 - mnew) +
                       __expf(v2 - mnew) + __expf(v3 - mnew);
            ps += __shfl_xor(ps, 1, 64);
            ps += __shfl_xor(ps, 2, 64);
            ps += __shfl_xor(ps, 4, 64);
            ps += __shfl_xor(ps, 8, 64);

            s_r[j] = s_r[j] * __expf(m_r[j] - mnew) + ps;
            m_r[j] = mnew;
        }
    }

    float inv_s[4];
#pragma unroll
    for (int j = 0; j < 4; ++j) inv_s[j] = 1.f / s_r[j];

    f32x4 cacc[4] = {};   // ctx accumulator: [d-frag], rows lg*4+j

    const int vr = tid >> 2;        // V staging: row 0..63
    const int vq = tid & 3;

    // ---------------- pass 2: attn write + PV ----------------
    for (int kt = 0; kt <= qt; ++kt) {
        const int k0 = kt * 64;

        // V staging loads (coalesced 64B rows) — issue before compute
        uint4 vraw[4];
#pragma unroll
        for (int i = 0; i < 4; ++i)
            vraw[i] = *reinterpret_cast<const uint4*>(
                vh_head + (size_t)(k0 + vr) * DEPTH + (vq + 4 * i) * 4);

        f32x4 sacc[4] = {};
        qk_tile(kh_head, k0, l15, lg, qhi, qlo, sacc);

        const bool diag = (kt == qt);
        uint32_t ppk[4][4];   // [fc][j]
#pragma unroll
        for (int j = 0; j < 4; ++j) {
            const int qg = q0 + wid * 16 + lg * 4 + j;
            float* arow = attn + ((size_t)(b * Hn + h) * Sdim + qg) * Sdim;
#pragma unroll
            for (int fc = 0; fc < 4; ++fc) {
                const int col = k0 + fc * 16 + l15;
                float p = __expf(sacc[fc][j] - m_r[j]) * inv_s[j];
                if (diag && col > qg) p = 0.f;
                arow[col] = p;
                ppk[fc][j] = pack_hl(p);
            }
        }

        __syncthreads();   // prev-tile PV reads of Vt/Ps complete

        // stage V transposed (2-way banks w/ stride-68 pad)
#pragma unroll
        for (int i = 0; i < 4; ++i) {
            const int c0 = (vq + 4 * i) * 4;
            Vt[c0 + 0][vr] = vraw[i].x;
            Vt[c0 + 1][vr] = vraw[i].y;
            Vt[c0 + 2][vr] = vraw[i].z;
            Vt[c0 + 3][vr] = vraw[i].w;
        }
        // stage P packed [qrow][key]
#pragma unroll
        for (int j = 0; j < 4; ++j)
#pragma unroll
            for (int fc = 0; fc < 4; ++fc)
                Ps[wid * 16 + lg * 4 + j][fc * 16 + l15] = ppk[fc][j];

        __syncthreads();

        // PV: ctx += P @ V  (A from Ps rows, B from Vt rows; same slot order)
#pragma unroll
        for (int kk = 0; kk < 2; ++kk) {
            const uint32_t* pap = &Ps[wid * 16 + l15][kk * 32 + lg * 8];
            const uint4 a0 = *reinterpret_cast<const uint4*>(pap);
            const uint4 a1 = *reinterpret_cast<const uint4*>(pap + 4);
            short8v phi, plo;
            unpack_frag(a0, a1, phi, plo);
#pragma unroll
            for (int fc = 0; fc < 4; ++fc) {
                const uint32_t* pbp = &Vt[fc * 16 + l15][kk * 32 + lg * 8];
                const uint4 b0 = *reinterpret_cast<const uint4*>(pbp);
                const uint4 b1 = *reinterpret_cast<const uint4*>(pbp + 4);
                short8v vhi, vlo;
                unpack_frag(b0, b1, vhi, vlo);
                cacc[fc] = __builtin_amdgcn_mfma_f32_16x16x32_bf16(phi, vhi, cacc[fc], 0, 0, 0);
                cacc[fc] = __builtin_amdgcn_mfma_f32_16x16x32_bf16(phi, vlo, cacc[fc], 0, 0, 0);
                cacc[fc] = __builtin_amdgcn_mfma_f32_16x16x32_bf16(plo, vhi, cacc[fc], 0, 0, 0);
            }
        }
    }

    // ctx in concat layout (B, S, D)
#pragma unroll
    for (int fc = 0; fc < 4; ++fc)
#pragma unroll
        for (int j = 0; j < 4; ++j) {
            const int qg = q0 + wid * 16 + lg * 4 + j;
            ctx[((size_t)b * Sdim + qg) * Ddim + h * DEPTH + fc * 16 + l15] =
                cacc[fc][j];
        }
}

// ---------------------------------------------------------------------------
extern "C" void kernel_launch(void* const* d_in, const int* in_sizes, int n_in,
                              void* d_out, int out_size, void* d_ws, size_t ws_size,
                              hipStream_t stream)
{
    (void)in_sizes; (void)n_in; (void)out_size; (void)ws_size;

    const float* v  = (const float*)d_in[0];
    const float* k  = (const float*)d_in[1];
    const float* q  = (const float*)d_in[2];
    const float* Wq = (const float*)d_in[4];
    const float* bq = (const float*)d_in[5];
    const float* Wk = (const float*)d_in[6];
    const float* bk = (const float*)d_in[7];
    const float* Wv = (const float*)d_in[8];
    const float* bv = (const float*)d_in[9];
    const float* Wo = (const float*)d_in[10];
    const float* bo = (const float*)d_in[11];

    float* out  = (float*)d_out;
    float* attn = out + (size_t)Bsz * Sdim * Ddim;

    const size_t sz = (size_t)Bsz * Sdim * Ddim;
    float* ws  = (float*)d_ws;
    uint32_t* qh = (uint32_t*)ws;            // packed hi|lo
    uint32_t* kh = qh + sz;
    uint32_t* vh = kh + sz;
    float*   ctx = (float*)(vh + sz);

    // Weight-pack aliasing (stream-ordered): WtQ/K/V live in the ctx region,
    // consumed by proj before attn writes ctx.  WtO lives in the qh region,
    // packed only after attn has consumed qh.
    uint32_t* WtQ = (uint32_t*)ctx;
    uint32_t* WtK = WtQ + 1024 * 1024;
    uint32_t* WtV = WtK + 1024 * 1024;
    uint32_t* WtO = qh;

    dim3 gpk(16, 16);
    pack_w_kernel<<<gpk, 256, 0, stream>>>(Wq, WtQ);
    pack_w_kernel<<<gpk, 256, 0, stream>>>(Wk, WtK);
    pack_w_kernel<<<gpk, 256, 0, stream>>>(Wv, WtV);

    dim3 gproj(Ddim / 128, Mrows / 128, 3);
    proj_kernel<<<gproj, 256, 0, stream>>>(q, k, v, WtQ, WtK, WtV,
                                           bq, bk, bv, qh, kh, vh);

    attn_mfma_kernel<<<dim3(QTILES * Hn * Bsz), 256, 0, stream>>>(
        qh, kh, vh, attn, ctx);

    pack_w_kernel<<<gpk, 256, 0, stream>>>(Wo, WtO);

    dim3 gout(Ddim / 128, Mrows / 128);
    oproj_kernel<<<gout, 256, 0, stream>>>(ctx, WtO, bo, out);
}